// Round 2
// baseline (10278.828 us; speedup 1.0000x reference)
//
#include <hip/hip_runtime.h>
#include <stdint.h>
#include <stddef.h>

#define Bsz 1024
#define Tsz 512
#define Dsz 256
#define Hsz 256
#define G3  768

typedef __bf16 bf16;
typedef __attribute__((ext_vector_type(8))) __bf16 bf16x8;
typedef __attribute__((ext_vector_type(4))) float f32x4;

__device__ __forceinline__ float bf2f(bf16 v) { return (float)v; }

// ---------------- weight fp32 -> bf16 convert ----------------
__global__ void k_cvtw(const float* __restrict__ Wx, const float* __restrict__ Wh,
                       const float* __restrict__ Wa, bf16* __restrict__ o) {
  int i = blockIdx.x * 256 + threadIdx.x;   // grid covers exactly 524288
  const int NX = G3 * Dsz;   // 196608
  const int NH = G3 * Hsz;   // 196608
  if (i < NX) o[i] = (bf16)Wx[i];
  else if (i < NX + NH) o[i] = (bf16)Wh[i - NX];
  else o[i] = (bf16)Wa[i - NX - NH];
}

// ---------------- phase 1: gx[tloc][b][0:768] = x[b][t] @ Wx^T + bx (bf16) ----------------
__global__ __launch_bounds__(256) void k_phase1(
    const float* __restrict__ x, const bf16* __restrict__ wxb,
    const float* __restrict__ bx, bf16* __restrict__ gx,
    int t0, int tpb) {
  __shared__ bf16 xs[64 * 256];   // swizzled rows of 512B
  int tid = threadIdx.x;
  int b  = blockIdx.x / tpb;
  int tb = blockIdx.x % tpb;
  int tbase = t0 + tb * 64;
  const float* xsrc = x + ((size_t)b * Tsz + tbase) * Dsz;
  #pragma unroll
  for (int i = 0; i < 8; ++i) {
    int c = tid + 256 * i;
    int row = c >> 5;
    int col = (c & 31) * 8;
    float4 f0 = *(const float4*)(xsrc + row * 256 + col);
    float4 f1 = *(const float4*)(xsrc + row * 256 + col + 4);
    union { bf16 h[8]; uint32_t u[4]; } p;
    p.h[0] = (bf16)f0.x; p.h[1] = (bf16)f0.y; p.h[2] = (bf16)f0.z; p.h[3] = (bf16)f0.w;
    p.h[4] = (bf16)f1.x; p.h[5] = (bf16)f1.y; p.h[6] = (bf16)f1.z; p.h[7] = (bf16)f1.w;
    int off = row * 512 + ((col * 2) ^ ((row & 7) << 4));
    *(uint4*)((char*)xs + off) = *(const uint4*)p.u;
  }
  __syncthreads();
  int w = tid >> 6, l = tid & 63;
  int lr = l & 15, lq = l >> 4;
  int arow = (w << 4) + lr;
  int asw = (arow & 7) << 4;
  bf16x8 A[8];
  #pragma unroll
  for (int k = 0; k < 8; ++k)   // FIX: XOR applied to the FULL in-row byte offset
    A[k] = *(const bf16x8*)((const char*)xs + arow * 512 + ((lq * 16 + 64 * k) ^ asw));
  const bf16* bsrc = wxb + lr * Dsz + lq * 8;
  int tloc_base = tb * 64 + (w << 4);
  #pragma unroll 1
  for (int ch = 0; ch < 6; ++ch) {
    f32x4 acc[8];
    #pragma unroll
    for (int tt = 0; tt < 8; ++tt) {
      float bias = bx[(ch * 8 + tt) * 16 + lr];
      #pragma unroll
      for (int e = 0; e < 4; ++e) acc[tt][e] = bias;
    }
    #pragma unroll
    for (int tt = 0; tt < 8; ++tt) {
      const bf16* bp = bsrc + (size_t)((ch * 8 + tt) * 16) * Dsz;
      #pragma unroll
      for (int k = 0; k < 8; ++k) {
        bf16x8 Bf = *(const bf16x8*)(bp + 32 * k);
        acc[tt] = __builtin_amdgcn_mfma_f32_16x16x32_bf16(A[k], Bf, acc[tt], 0, 0, 0);
      }
    }
    #pragma unroll
    for (int tt = 0; tt < 8; ++tt) {
      int n = (ch * 8 + tt) * 16 + lr;
      #pragma unroll
      for (int j = 0; j < 4; ++j) {
        int row16 = lq * 4 + j;
        size_t off = ((size_t)(tloc_base + row16) * Bsz + b) * G3 + n;
        gx[off] = (bf16)acc[tt][j];
      }
    }
  }
}

// ---------------- phase 2: sequential GRU scan, 16 batch rows per block ----------------
__global__ __launch_bounds__(512, 2) void k_phase2(
    const bf16* __restrict__ gx, const bf16* __restrict__ whb,
    const bf16* __restrict__ wab, const float* __restrict__ bh,
    const float* __restrict__ ba, float* __restrict__ out,
    float* __restrict__ hstate, int t0, int TC) {
  __shared__ bf16 slab[16 * 768];   // gx rows, swizzled within 1536B rows
  __shared__ bf16 hb[16 * 256];     // h_{t-1} bf16, swizzled 512B rows
  __shared__ bf16 hi[16 * 256];     // h_i (gh middle) bf16, swizzled
  int tid = threadIdx.x;
  int w = tid >> 6, l = tid & 63;
  int b0 = blockIdx.x << 4;
  int lr = l & 15, lq = l >> 4;
  int asw = (lr & 7) << 4;          // swizzle key for A-frag reads (row = lr)
  const bf16* whB = whb + (size_t)lr * Hsz + lq * 8;
  const bf16* waB = wab + (size_t)lr * (2 * Hsz) + lq * 8;
  float bR[2], bI[2], bN[2], bA[2];
  #pragma unroll
  for (int i = 0; i < 2; ++i) {
    int n0 = 32 * w + 16 * i;
    bR[i] = bh[n0 + lr];
    bI[i] = bh[256 + n0 + lr];
    bN[i] = bh[512 + n0 + lr];
    bA[i] = ba[n0 + lr];
  }
  const char* gxb = (const char*)gx + (size_t)b0 * 1536;
  int srow = tid >> 5;
  int scb  = (tid & 31) * 48;
  int sdst = srow * 1536;
  int ssw  = (srow & 7) << 4;

  float h[8];
  { // prologue: stage slab for local t=0, init h and hb
    uint4 st[3];
    const char* src = gxb + srow * 1536 + scb;
    #pragma unroll
    for (int u = 0; u < 3; ++u) st[u] = *(const uint4*)(src + 16 * u);
    if (t0 == 0) {
      #pragma unroll
      for (int e = 0; e < 8; ++e) h[e] = 0.f;
    } else {
      #pragma unroll
      for (int i = 0; i < 2; ++i)
        #pragma unroll
        for (int j = 0; j < 4; ++j) {
          int row = 4 * lq + j, col = 32 * w + 16 * i + lr;
          h[i * 4 + j] = hstate[(size_t)(b0 + row) * Hsz + col];
        }
    }
    #pragma unroll
    for (int i = 0; i < 2; ++i)
      #pragma unroll
      for (int j = 0; j < 4; ++j) {
        int row = 4 * lq + j, col = 32 * w + 16 * i + lr;
        *(bf16*)((char*)hb + row * 512 + ((2 * col) ^ ((row & 7) << 4))) = (bf16)h[i * 4 + j];
      }
    #pragma unroll
    for (int u = 0; u < 3; ++u) {
      int cb = scb + 16 * u;
      *(uint4*)((char*)slab + sdst + (cb ^ ssw)) = st[u];
    }
  }
  __syncthreads();

  for (int t = 0; t < TC; ++t) {
    uint4 st[3];
    bool pf = (t + 1 < TC);
    if (pf) { // issue next-step gx loads early; latency hides under GEMMs
      const char* src = gxb + (size_t)(t + 1) * Bsz * 1536 + srow * 1536 + scb;
      #pragma unroll
      for (int u = 0; u < 3; ++u) st[u] = *(const uint4*)(src + 16 * u);
    }
    // ---- gh = h @ Wh^T + bh ----
    bf16x8 Ah[8];
    #pragma unroll
    for (int k = 0; k < 8; ++k)   // FIX: full-offset XOR
      Ah[k] = *(const bf16x8*)((const char*)hb + lr * 512 + ((lq * 16 + 64 * k) ^ asw));
    f32x4 accR[2], accI[2], accN[2];
    #pragma unroll
    for (int i = 0; i < 2; ++i) {
      int n0 = 32 * w + 16 * i;
      #pragma unroll
      for (int e = 0; e < 4; ++e) { accR[i][e] = bR[i]; accI[i][e] = bI[i]; accN[i][e] = bN[i]; }
      const bf16* bpR = whB + (size_t)n0 * Hsz;
      const bf16* bpI = whB + (size_t)(256 + n0) * Hsz;
      const bf16* bpN = whB + (size_t)(512 + n0) * Hsz;
      #pragma unroll
      for (int k = 0; k < 8; ++k)
        accR[i] = __builtin_amdgcn_mfma_f32_16x16x32_bf16(Ah[k], *(const bf16x8*)(bpR + 32 * k), accR[i], 0, 0, 0);
      #pragma unroll
      for (int k = 0; k < 8; ++k)
        accI[i] = __builtin_amdgcn_mfma_f32_16x16x32_bf16(Ah[k], *(const bf16x8*)(bpI + 32 * k), accI[i], 0, 0, 0);
      #pragma unroll
      for (int k = 0; k < 8; ++k)
        accN[i] = __builtin_amdgcn_mfma_f32_16x16x32_bf16(Ah[k], *(const bf16x8*)(bpN + 32 * k), accN[i], 0, 0, 0);
    }
    // write h_i (bf16) for attention A-operand
    #pragma unroll
    for (int i = 0; i < 2; ++i)
      #pragma unroll
      for (int j = 0; j < 4; ++j) {
        int row = 4 * lq + j, col = 32 * w + 16 * i + lr;
        *(bf16*)((char*)hi + row * 512 + ((2 * col) ^ ((row & 7) << 4))) = (bf16)accI[i][j];
      }
    __syncthreads();
    // ---- att = [i_i, h_i] @ Wa^T + ba ----
    bf16x8 Ai[8], Av[8];
    #pragma unroll
    for (int k = 0; k < 8; ++k)   // FIX: full-offset XOR (i_i region starts at byte 512)
      Ai[k] = *(const bf16x8*)((const char*)slab + lr * 1536 + 512 + ((lq * 16 + 64 * k) ^ asw));
    #pragma unroll
    for (int k = 0; k < 8; ++k)   // FIX: full-offset XOR
      Av[k] = *(const bf16x8*)((const char*)hi + lr * 512 + ((lq * 16 + 64 * k) ^ asw));
    f32x4 accA[2];
    #pragma unroll
    for (int i = 0; i < 2; ++i) {
      int n0 = 32 * w + 16 * i;
      #pragma unroll
      for (int e = 0; e < 4; ++e) accA[i][e] = bA[i];
      const bf16* bp = waB + (size_t)n0 * (2 * Hsz);
      #pragma unroll
      for (int s = 0; s < 8; ++s)
        accA[i] = __builtin_amdgcn_mfma_f32_16x16x32_bf16(Ai[s], *(const bf16x8*)(bp + 32 * s), accA[i], 0, 0, 0);
      #pragma unroll
      for (int s = 0; s < 8; ++s)
        accA[i] = __builtin_amdgcn_mfma_f32_16x16x32_bf16(Av[s], *(const bf16x8*)(bp + 256 + 32 * s), accA[i], 0, 0, 0);
    }
    // ---- elementwise gates, all in registers ----
    #pragma unroll
    for (int i = 0; i < 2; ++i)
      #pragma unroll
      for (int j = 0; j < 4; ++j) {
        int row = 4 * lq + j, col = 32 * w + 16 * i + lr;
        int sw = (row & 7) << 4;
        float ir  = bf2f(*(const bf16*)((const char*)slab + row * 1536 + ((2 * col) ^ sw)));
        float inn = bf2f(*(const bf16*)((const char*)slab + row * 1536 + 1024 + ((2 * col) ^ sw)));
        float rg = 1.f / (1.f + __expf(-(ir + accR[i][j])));
        float xx = inn + rg * accN[i][j];
        xx = fminf(fmaxf(xx, -30.f), 30.f);
        float e2 = __expf(-2.f * xx);
        float ng = (1.f - e2) / (1.f + e2);
        float ig = 1.f / (1.f + __expf(-accA[i][j]));
        float hy = ng + ig * (h[i * 4 + j] - ng);
        h[i * 4 + j] = hy;
        out[((size_t)(b0 + row) * Tsz + (t0 + t)) * Hsz + col] = hy;
      }
    __syncthreads();
    // ---- writes for next step ----
    if (pf) {
      #pragma unroll
      for (int u = 0; u < 3; ++u) {
        int cb = scb + 16 * u;
        *(uint4*)((char*)slab + sdst + (cb ^ ssw)) = st[u];
      }
    }
    #pragma unroll
    for (int i = 0; i < 2; ++i)
      #pragma unroll
      for (int j = 0; j < 4; ++j) {
        int row = 4 * lq + j, col = 32 * w + 16 * i + lr;
        *(bf16*)((char*)hb + row * 512 + ((2 * col) ^ ((row & 7) << 4))) = (bf16)h[i * 4 + j];
      }
    __syncthreads();
  }
  // persist h for next chunk launch
  #pragma unroll
  for (int i = 0; i < 2; ++i)
    #pragma unroll
    for (int j = 0; j < 4; ++j) {
      int row = 4 * lq + j, col = 32 * w + 16 * i + lr;
      hstate[(size_t)(b0 + row) * Hsz + col] = h[i * 4 + j];
    }
}

extern "C" void kernel_launch(void* const* d_in, const int* in_sizes, int n_in,
                              void* d_out, int out_size, void* d_ws, size_t ws_size,
                              hipStream_t stream) {
  (void)in_sizes; (void)n_in; (void)out_size;
  const float* x  = (const float*)d_in[0];
  const float* Wx = (const float*)d_in[1];
  const float* bx = (const float*)d_in[2];
  const float* Wh = (const float*)d_in[3];
  const float* bh = (const float*)d_in[4];
  const float* Wa = (const float*)d_in[5];
  const float* ba = (const float*)d_in[6];
  float* out = (float*)d_out;
  char* ws = (char*)d_ws;

  bf16* wxb = (bf16*)ws;                       // 393216 B
  bf16* whb = (bf16*)(ws + 393216);            // 393216 B
  bf16* wab = (bf16*)(ws + 786432);            // 262144 B
  float* hstate = (float*)(ws + 1048576);      // 1 MB
  bf16* gxbuf = (bf16*)(ws + 2097152);

  size_t avail = (ws_size > 2097152) ? ws_size - 2097152 : 0;
  size_t per_t = (size_t)Bsz * G3 * 2;         // 1.5 MB per timestep
  long tcl = (long)(avail / per_t);
  int TC = (tcl > Tsz) ? Tsz : (int)tcl;
  TC &= ~63;
  if (TC < 64) TC = 64;                        // minimum chunk

  k_cvtw<<<dim3(2048), dim3(256), 0, stream>>>(Wx, Wh, Wa, wxb);
  for (int t0 = 0; t0 < Tsz; t0 += TC) {
    int tc = Tsz - t0; if (tc > TC) tc = TC;
    int tpb = tc >> 6;
    k_phase1<<<dim3(Bsz * tpb), dim3(256), 0, stream>>>(x, wxb, bx, gxbuf, t0, tpb);
    k_phase2<<<dim3(64), dim3(512), 0, stream>>>(gxbuf, whb, wab, bh, ba, out, hstate, t0, tc);
  }
}

// Round 3
// 4176.249 us; speedup vs baseline: 2.4613x; 2.4613x over previous
//
#include <hip/hip_runtime.h>
#include <stdint.h>
#include <stddef.h>

#define Bsz 1024
#define Tsz 512
#define Dsz 256
#define Hsz 256
#define G3  768
#define SLAB 24576   // bytes per (t, batch-group-of-16) gx slab: [r 8K][i 8K][n 8K]

typedef __bf16 bf16;
typedef __attribute__((ext_vector_type(8))) __bf16 bf16x8;
typedef __attribute__((ext_vector_type(4))) float f32x4;

__device__ __forceinline__ float bf2f(bf16 v) { return (float)v; }

// ============ repack Wx, Wh(R,N), Wa_i into MFMA-fragment-major bf16 ============
// frag layout for a (16-col-tile, k') B-frag: 1KB block, elem off = lq*128 + lr*8 + e
// dst element offset = g*8 where g = ((tile*8+kp)*4+lq)*16+lr
__global__ __launch_bounds__(256) void k_repack(
    const float* __restrict__ Wx, const float* __restrict__ Wh,
    const float* __restrict__ Wa,
    bf16* __restrict__ wxf, bf16* __restrict__ whf, bf16* __restrict__ waf) {
  int g = blockIdx.x * 256 + threadIdx.x;   // 49152 total
  const float* s; bf16* d;
  if (g < 24576) {            // Wx: 48 tiles (rows 0..767), K=256
    int lr = g & 15, lq = (g >> 4) & 3, kp = (g >> 6) & 7, tile = g >> 9;
    s = Wx + (tile * 16 + lr) * 256 + kp * 32 + lq * 8;
    d = wxf + g * 8;
  } else if (g < 40960) {     // Wh R (tiles 0..15 = rows 0..255), N (tiles 16..31 = rows 512..767)
    int gg = g - 24576;
    int lr = gg & 15, lq = (gg >> 4) & 3, kp = (gg >> 6) & 7, tile = gg >> 9;
    int row = (tile < 16) ? (tile * 16 + lr) : (512 + (tile - 16) * 16 + lr);
    s = Wh + row * 256 + kp * 32 + lq * 8;
    d = whf + gg * 8;
  } else {                    // Wa_i: 16 tiles (rows 0..255), K = first 256 of 512
    int gg = g - 40960;
    int lr = gg & 15, lq = (gg >> 4) & 3, kp = (gg >> 6) & 7, tile = gg >> 9;
    s = Wa + (tile * 16 + lr) * 512 + kp * 32 + lq * 8;
    d = waf + gg * 8;
  }
  #pragma unroll
  for (int e = 0; e < 8; ++e) d[e] = (bf16)s[e];
}

// ============ Wc = Wa_h @ Wh_I (256x256) -> bf16 frags; c0 = ba + Wa_h @ bh_I ============
__global__ __launch_bounds__(256) void k_wc(
    const float* __restrict__ Wa, const float* __restrict__ Wh,
    const float* __restrict__ bh, const float* __restrict__ ba,
    bf16* __restrict__ wcf, float* __restrict__ c0) {
  __shared__ float red[256];
  int n = blockIdx.x, k = threadIdx.x;
  float acc = 0.f;
  for (int m = 0; m < 256; ++m)
    acc += Wa[n * 512 + 256 + m] * Wh[(256 + m) * 256 + k];
  int kp = k >> 5, lq = (k >> 3) & 3, e = k & 7;
  int ti = n >> 4, lr = n & 15;
  wcf[(ti * 8 + kp) * 512 + lq * 128 + lr * 8 + e] = (bf16)acc;
  red[k] = Wa[n * 512 + 256 + k] * bh[256 + k];
  __syncthreads();
  for (int s = 128; s > 0; s >>= 1) {
    if (k < s) red[k] += red[k + s];
    __syncthreads();
  }
  if (k == 0) c0[n] = ba[n] + red[0];
}

// ============ phase 1: gx = x @ Wx^T + (bx [+ bh for r-region]), phase2-layout ============
__global__ __launch_bounds__(256) void k_phase1(
    const float* __restrict__ x, const bf16* __restrict__ wxf,
    const float* __restrict__ bx, const float* __restrict__ bh,
    bf16* __restrict__ gx, int t0, int tpb) {
  __shared__ bf16 xs[64 * 256];   // swizzled rows of 512B
  int tid = threadIdx.x;
  int b  = blockIdx.x / tpb;
  int tb = blockIdx.x % tpb;
  int tbase = t0 + tb * 64;
  const float* xsrc = x + ((size_t)b * Tsz + tbase) * Dsz;
  #pragma unroll
  for (int i = 0; i < 8; ++i) {
    int c = tid + 256 * i;
    int row = c >> 5;
    int col = (c & 31) * 8;
    float4 f0 = *(const float4*)(xsrc + row * 256 + col);
    float4 f1 = *(const float4*)(xsrc + row * 256 + col + 4);
    union { bf16 h[8]; uint32_t u[4]; } p;
    p.h[0] = (bf16)f0.x; p.h[1] = (bf16)f0.y; p.h[2] = (bf16)f0.z; p.h[3] = (bf16)f0.w;
    p.h[4] = (bf16)f1.x; p.h[5] = (bf16)f1.y; p.h[6] = (bf16)f1.z; p.h[7] = (bf16)f1.w;
    int off = row * 512 + ((col * 2) ^ ((row & 7) << 4));
    *(uint4*)((char*)xs + off) = *(const uint4*)p.u;
  }
  __syncthreads();
  int w = tid >> 6, l = tid & 63;
  int lr = l & 15, lq = l >> 4;
  int arow = (w << 4) + lr;
  int asw = (arow & 7) << 4;
  bf16x8 A[8];
  #pragma unroll
  for (int k = 0; k < 8; ++k)
    A[k] = *(const bf16x8*)((const char*)xs + arow * 512 + ((lq * 16 + 64 * k) ^ asw));
  const bf16* bsrc = wxf + lq * 128 + lr * 8;
  int tloc_base = tb * 64 + (w << 4);
  int br = b & 15, bg = b >> 4;
  #pragma unroll 1
  for (int ch = 0; ch < 6; ++ch) {
    f32x4 acc[8];
    #pragma unroll
    for (int tt = 0; tt < 8; ++tt) {
      int n = (ch * 8 + tt) * 16 + lr;
      float bias = bx[n] + (n < 256 ? bh[n] : 0.f);   // fold bh_r into gx_r
      #pragma unroll
      for (int e = 0; e < 4; ++e) acc[tt][e] = bias;
    }
    #pragma unroll
    for (int tt = 0; tt < 8; ++tt) {
      int tile = ch * 8 + tt;
      #pragma unroll
      for (int k = 0; k < 8; ++k) {
        bf16x8 Bf = *(const bf16x8*)(bsrc + (tile * 8 + k) * 512);
        acc[tt] = __builtin_amdgcn_mfma_f32_16x16x32_bf16(A[k], Bf, acc[tt], 0, 0, 0);
      }
    }
    #pragma unroll
    for (int tt = 0; tt < 8; ++tt) {
      int n = (ch * 8 + tt) * 16 + lr;
      int off;
      if (n < 256)        off = (n >> 4) * 512 + (br >> 2) * 128 + (n & 15) * 8 + (br & 3) * 2;
      else if (n < 512) { int c = n - 256;
                          off = 8192 + (c >> 5) * 1024 + ((c >> 3) & 3) * 256 + br * 16 + (c & 7) * 2; }
      else              { int c = n - 512;
                          off = 16384 + (c >> 4) * 512 + (br >> 2) * 128 + (c & 15) * 8 + (br & 3) * 2; }
      #pragma unroll
      for (int j = 0; j < 4; ++j) {
        int tl = tloc_base + lq * 4 + j;
        *(bf16*)((char*)gx + ((size_t)tl * 64 + bg) * SLAB + off) = (bf16)acc[tt][j];
      }
    }
  }
}

// ============ phase 2: sequential scan; Wh in regs, Wc in LDS, Wa_i streamed ============
__global__ __launch_bounds__(512, 2) void k_phase2(
    const bf16* __restrict__ gx, const bf16* __restrict__ whf,
    const bf16* __restrict__ waf, const bf16* __restrict__ wcf,
    const float* __restrict__ bh, const float* __restrict__ c0,
    float* __restrict__ out, float* __restrict__ hstate, int t0, int TC) {
  extern __shared__ char lds[];          // [0,131072): Wc frags; [131072,+16384): hb dbuf
  char* hbase = lds + 131072;
  int tid = threadIdx.x;
  int w = tid >> 6, l = tid & 63, lr = l & 15, lq = l >> 4;
  int bg = blockIdx.x, b0 = bg << 4;

  // stage Wc into LDS (linear copy, frag-major already)
  #pragma unroll 4
  for (int it = 0; it < 16; ++it)
    *(uint4*)(lds + it * 8192 + tid * 16) =
        *(const uint4*)((const char*)wcf + it * 8192 + tid * 16);

  // Wh R,N fragments -> registers (held across all timesteps)
  const bf16* whbase = whf + lq * 128 + lr * 8;
  bf16x8 whR[2][8], whN[2][8];
  #pragma unroll
  for (int i = 0; i < 2; ++i)
    #pragma unroll
    for (int k = 0; k < 8; ++k) {
      whR[i][k] = *(const bf16x8*)(whbase + ((w * 2 + i) * 8 + k) * 512);
      whN[i][k] = *(const bf16x8*)(whbase + ((16 + w * 2 + i) * 8 + k) * 512);
    }
  float bN[2], cA[2];
  #pragma unroll
  for (int i = 0; i < 2; ++i) {
    bN[i] = bh[512 + w * 32 + i * 16 + lr];
    cA[i] = c0[w * 32 + i * 16 + lr];
  }

  float h[2][4];
  if (t0 == 0) {
    #pragma unroll
    for (int i = 0; i < 2; ++i)
      #pragma unroll
      for (int j = 0; j < 4; ++j) h[i][j] = 0.f;
  } else {
    #pragma unroll
    for (int i = 0; i < 2; ++i)
      #pragma unroll
      for (int j = 0; j < 4; ++j)
        h[i][j] = hstate[(size_t)(b0 + lq * 4 + j) * Hsz + w * 32 + i * 16 + lr];
  }
  // write hb buf0 in A-frag layout: byte = (col>>5)*1024 + ((col>>3)&3)*256 + brow*16 + (col&7)*2
  #pragma unroll
  for (int i = 0; i < 2; ++i) {
    int colb = (2 * i + (lr >> 3)) & 3;
    char* hw = hbase + w * 1024 + colb * 256 + (lr & 7) * 2 + lq * 64;
    #pragma unroll
    for (int j = 0; j < 4; ++j) *(bf16*)(hw + j * 16) = (bf16)h[i][j];
  }
  __syncthreads();

  const char* gxb = (const char*)gx + (size_t)bg * SLAB;
  const bf16* wafw = waf + lq * 128 + lr * 8;

  for (int t = 0; t < TC; ++t) {
    const char* slab = gxb + (size_t)t * (64 * SLAB);
    int cur = t & 1, nxt = cur ^ 1;
    // ---- early independent global loads (hidden under GEMMs) ----
    bf16x8 Ai[8];
    #pragma unroll
    for (int k = 0; k < 8; ++k)
      Ai[k] = *(const bf16x8*)(slab + 8192 + k * 1024 + lq * 256 + lr * 16);
    uint2 irv[2], inv[2];
    #pragma unroll
    for (int i = 0; i < 2; ++i) {
      irv[i] = *(const uint2*)(slab + (w * 2 + i) * 512 + lq * 128 + lr * 8);
      inv[i] = *(const uint2*)(slab + 16384 + (w * 2 + i) * 512 + lq * 128 + lr * 8);
    }
    // ---- gh R/N (reg weights) + att-h (Wc from LDS) ----
    f32x4 accR[2], accN[2], accA[2];
    #pragma unroll
    for (int i = 0; i < 2; ++i)
      #pragma unroll
      for (int e = 0; e < 4; ++e) {
        accR[i][e] = 0.f; accN[i][e] = bN[i]; accA[i][e] = cA[i];
      }
    const char* hr = hbase + cur * 8192 + lq * 256 + lr * 16;
    #pragma unroll
    for (int kk = 0; kk < 8; ++kk) {
      bf16x8 Ah = *(const bf16x8*)(hr + kk * 1024);
      accR[0] = __builtin_amdgcn_mfma_f32_16x16x32_bf16(Ah, whR[0][kk], accR[0], 0, 0, 0);
      accR[1] = __builtin_amdgcn_mfma_f32_16x16x32_bf16(Ah, whR[1][kk], accR[1], 0, 0, 0);
      accN[0] = __builtin_amdgcn_mfma_f32_16x16x32_bf16(Ah, whN[0][kk], accN[0], 0, 0, 0);
      accN[1] = __builtin_amdgcn_mfma_f32_16x16x32_bf16(Ah, whN[1][kk], accN[1], 0, 0, 0);
      bf16x8 wc0 = *(const bf16x8*)(lds + ((w * 2 + 0) * 8 + kk) * 1024 + lq * 256 + lr * 16);
      accA[0] = __builtin_amdgcn_mfma_f32_16x16x32_bf16(Ah, wc0, accA[0], 0, 0, 0);
      bf16x8 wc1 = *(const bf16x8*)(lds + ((w * 2 + 1) * 8 + kk) * 1024 + lq * 256 + lr * 16);
      accA[1] = __builtin_amdgcn_mfma_f32_16x16x32_bf16(Ah, wc1, accA[1], 0, 0, 0);
    }
    // ---- att-i: Ai (global) x Wa_i (streamed frag-major, coalesced 1KB/wave) ----
    #pragma unroll
    for (int kk = 0; kk < 8; ++kk) {
      bf16x8 wa0 = *(const bf16x8*)(wafw + ((w * 2 + 0) * 8 + kk) * 512);
      accA[0] = __builtin_amdgcn_mfma_f32_16x16x32_bf16(Ai[kk], wa0, accA[0], 0, 0, 0);
      bf16x8 wa1 = *(const bf16x8*)(wafw + ((w * 2 + 1) * 8 + kk) * 512);
      accA[1] = __builtin_amdgcn_mfma_f32_16x16x32_bf16(Ai[kk], wa1, accA[1], 0, 0, 0);
    }
    // ---- gates in registers ----
    #pragma unroll
    for (int i = 0; i < 2; ++i) {
      union { uint2 u; bf16 v[4]; } ir, in_;
      ir.u = irv[i]; in_.u = inv[i];
      #pragma unroll
      for (int j = 0; j < 4; ++j) {
        float rg = 1.f / (1.f + __expf(-(bf2f(ir.v[j]) + accR[i][j])));
        float xx = bf2f(in_.v[j]) + rg * accN[i][j];
        xx = fminf(fmaxf(xx, -30.f), 30.f);
        float e2 = __expf(-2.f * xx);
        float ng = (1.f - e2) / (1.f + e2);
        float ig = 1.f / (1.f + __expf(-accA[i][j]));
        float hy = ng + ig * (h[i][j] - ng);
        h[i][j] = hy;
        out[((size_t)(b0 + lq * 4 + j) * Tsz + (t0 + t)) * Hsz + (w * 32 + i * 16 + lr)] = hy;
      }
      int colb = (2 * i + (lr >> 3)) & 3;
      char* hw = hbase + nxt * 8192 + w * 1024 + colb * 256 + (lr & 7) * 2 + lq * 64;
      #pragma unroll
      for (int j = 0; j < 4; ++j) *(bf16*)(hw + j * 16) = (bf16)h[i][j];
    }
    __syncthreads();
  }
  // persist h for next chunk launch
  #pragma unroll
  for (int i = 0; i < 2; ++i)
    #pragma unroll
    for (int j = 0; j < 4; ++j)
      hstate[(size_t)(b0 + lq * 4 + j) * Hsz + w * 32 + i * 16 + lr] = h[i][j];
}

extern "C" void kernel_launch(void* const* d_in, const int* in_sizes, int n_in,
                              void* d_out, int out_size, void* d_ws, size_t ws_size,
                              hipStream_t stream) {
  (void)in_sizes; (void)n_in; (void)out_size;
  const float* x  = (const float*)d_in[0];
  const float* Wx = (const float*)d_in[1];
  const float* bx = (const float*)d_in[2];
  const float* Wh = (const float*)d_in[3];
  const float* bh = (const float*)d_in[4];
  const float* Wa = (const float*)d_in[5];
  const float* ba = (const float*)d_in[6];
  float* out = (float*)d_out;
  char* ws = (char*)d_ws;

  bf16* wxf = (bf16*)ws;                        // 393216 B
  bf16* whf = (bf16*)(ws + 393216);             // 262144 B (R + N only)
  bf16* waf = (bf16*)(ws + 655360);             // 131072 B
  bf16* wcf = (bf16*)(ws + 786432);             // 131072 B
  float* c0 = (float*)(ws + 917504);            // 1024 B
  float* hstate = (float*)(ws + 1048576);       // 1 MB
  bf16* gxbuf = (bf16*)(ws + 2097152);

  size_t avail = (ws_size > 2097152) ? ws_size - 2097152 : 0;
  size_t per_t = (size_t)64 * SLAB;             // 1.5 MB per timestep
  long tcl = (long)(avail / per_t);
  int TC = (tcl > Tsz) ? Tsz : (int)tcl;
  TC &= ~63;
  if (TC < 64) TC = 64;

  (void)hipFuncSetAttribute((const void*)k_phase2,
                            hipFuncAttributeMaxDynamicSharedMemorySize, 147456);

  k_repack<<<dim3(192), dim3(256), 0, stream>>>(Wx, Wh, Wa, wxf, whf, waf);
  k_wc<<<dim3(256), dim3(256), 0, stream>>>(Wa, Wh, bh, ba, wcf, c0);
  for (int t0 = 0; t0 < Tsz; t0 += TC) {
    int tc = Tsz - t0; if (tc > TC) tc = TC;
    int tpb = tc >> 6;
    k_phase1<<<dim3(Bsz * tpb), dim3(256), 0, stream>>>(x, wxf, bx, bh, gxbuf, t0, tpb);
    k_phase2<<<dim3(64), dim3(512), 147456, stream>>>(gxbuf, whf, waf, wcf, bh, c0, out, hstate, t0, tc);
  }
}

// Round 4
// 2223.982 us; speedup vs baseline: 4.6218x; 1.8778x over previous
//
#include <hip/hip_runtime.h>
#include <stdint.h>
#include <stddef.h>

#define Bsz 1024
#define Tsz 512
#define Dsz 256
#define Hsz 256
#define SLAB 24576   // bytes per (t, batch-group-of-16) slab: [r 8K][n 8K][a 8K]

typedef __bf16 bf16;
typedef __attribute__((ext_vector_type(8))) __bf16 bf16x8;
typedef __attribute__((ext_vector_type(4))) float f32x4;

__device__ __forceinline__ float bf2f(bf16 v) { return (float)v; }
__device__ __forceinline__ float sigm(float x) {
  return __builtin_amdgcn_rcpf(1.f + exp2f(-1.4426950408889634f * x));
}

// ============ repack Wx(R,N), Wh(R,N) into MFMA-fragment-major bf16 ============
// B-frag for (tile, kp): lane(lq,lr) elem e = W[tile*16+lr, kp*32+lq*8+e]
__global__ __launch_bounds__(256) void k_repack(
    const float* __restrict__ Wx, const float* __restrict__ Wh,
    bf16* __restrict__ wxf, bf16* __restrict__ whf) {
  int g = blockIdx.x * 256 + threadIdx.x;   // 32768 total
  int gg = g & 16383;
  int lr = gg & 15, lq = (gg >> 4) & 3, kp = (gg >> 6) & 7, tile = gg >> 9;
  int row = (tile < 16) ? (tile * 16 + lr) : (512 + (tile - 16) * 16 + lr);  // R rows / N rows
  const float* s;
  bf16* d;
  if (g < 16384) { s = Wx + row * 256 + kp * 32 + lq * 8; d = wxf + gg * 8; }
  else           { s = Wh + row * 256 + kp * 32 + lq * 8; d = whf + gg * 8; }
  #pragma unroll
  for (int e = 0; e < 8; ++e) d[e] = (bf16)s[e];
}

// ============ Wc = Wa_h @ Wh_I ; Wp = Wa_i @ Wx_I ; c0 = ba + Wa_h@bh_I + Wa_i@bx_I ====
__global__ __launch_bounds__(256) void k_wc(
    const float* __restrict__ Wa, const float* __restrict__ Wh,
    const float* __restrict__ Wx, const float* __restrict__ bh,
    const float* __restrict__ bx, const float* __restrict__ ba,
    bf16* __restrict__ wcf, bf16* __restrict__ wxf, float* __restrict__ c0) {
  __shared__ float red[256];
  int n = blockIdx.x, k = threadIdx.x;
  float accC = 0.f, accP = 0.f;
  for (int m = 0; m < 256; ++m) {
    accC += Wa[n * 512 + 256 + m] * Wh[(256 + m) * 256 + k];
    accP += Wa[n * 512 + m]       * Wx[(256 + m) * 256 + k];
  }
  int kp = k >> 5, lq = (k >> 3) & 3, e = k & 7;
  int ti = n >> 4, lr = n & 15;
  wcf[(ti * 8 + kp) * 512 + lq * 128 + lr * 8 + e] = (bf16)accC;
  // Wp goes into wxf tiles 32..47 (phase1 col-tiles 32..47 = a-region)
  wxf[(((32 + ti) * 8) + kp) * 512 + lq * 128 + lr * 8 + e] = (bf16)accP;
  red[k] = Wa[n * 512 + 256 + k] * bh[256 + k] + Wa[n * 512 + k] * bx[256 + k];
  __syncthreads();
  for (int s = 128; s > 0; s >>= 1) {
    if (k < s) red[k] += red[k + s];
    __syncthreads();
  }
  if (k == 0) c0[n] = ba[n] + red[0];
}

// ============ phase 1: slab[t][bg] <- [x@WxR^T + bxr+bhr | x@WxN^T + bxn | x@Wp^T] ======
// block: 16 batch rows (bg) x 16 timesteps; 4 waves, wave w owns t = tch*16 + w*4 + m
__global__ __launch_bounds__(256, 2) void k_phase1(
    const float* __restrict__ x, const bf16* __restrict__ wxf,
    const float* __restrict__ bx, const float* __restrict__ bh,
    bf16* __restrict__ gx, int t0) {
  int tid = threadIdx.x;
  int w = tid >> 6, l = tid & 63, lr = l & 15, lq = l >> 4;
  int bg = blockIdx.x, b0 = bg << 4;
  int tch = blockIdx.y;

  // A-fragments for 4 timestep-tiles, held in registers (128 VGPR)
  bf16x8 Am[4][8];
  #pragma unroll
  for (int m = 0; m < 4; ++m) {
    int tglob = t0 + tch * 16 + w * 4 + m;
    const float* xp = x + ((size_t)(b0 + lr) * Tsz + tglob) * Dsz + lq * 8;
    #pragma unroll
    for (int kk = 0; kk < 8; ++kk) {
      float4 f0 = *(const float4*)(xp + kk * 32);
      float4 f1 = *(const float4*)(xp + kk * 32 + 4);
      bf16x8 a;
      a[0] = (bf16)f0.x; a[1] = (bf16)f0.y; a[2] = (bf16)f0.z; a[3] = (bf16)f0.w;
      a[4] = (bf16)f1.x; a[5] = (bf16)f1.y; a[6] = (bf16)f1.z; a[7] = (bf16)f1.w;
      Am[m][kk] = a;
    }
  }
  const bf16* bsrc = wxf + lq * 128 + lr * 8;
  #pragma unroll 1
  for (int ct = 0; ct < 48; ++ct) {
    float bias;
    if (ct < 16)      { int row = ct * 16 + lr;              bias = bx[row] + bh[row]; }
    else if (ct < 32) { int row = 512 + (ct - 16) * 16 + lr; bias = bx[row]; }
    else              bias = 0.f;
    f32x4 acc[4];
    #pragma unroll
    for (int m = 0; m < 4; ++m)
      #pragma unroll
      for (int e = 0; e < 4; ++e) acc[m][e] = bias;
    #pragma unroll
    for (int kk = 0; kk < 8; ++kk) {
      bf16x8 Bf = *(const bf16x8*)(bsrc + (ct * 8 + kk) * 512);
      #pragma unroll
      for (int m = 0; m < 4; ++m)
        acc[m] = __builtin_amdgcn_mfma_f32_16x16x32_bf16(Am[m][kk], Bf, acc[m], 0, 0, 0);
    }
    int region = ct >> 4, rct = ct & 15;
    #pragma unroll
    for (int m = 0; m < 4; ++m) {
      int tl = tch * 16 + w * 4 + m;
      union { bf16 v[4]; uint2 u; } p;
      #pragma unroll
      for (int j = 0; j < 4; ++j) p.v[j] = (bf16)acc[m][j];
      *(uint2*)((char*)gx + ((size_t)tl * 64 + bg) * SLAB + region * 8192 +
                rct * 512 + lq * 128 + lr * 8) = p.u;
    }
  }
}

// ============ phase 2: sequential scan; Wh R/N in regs, Wc in LDS, ZERO weight stream ===
__global__ __launch_bounds__(512, 1) void k_phase2(
    const bf16* __restrict__ gx, const bf16* __restrict__ whf,
    const bf16* __restrict__ wcf, const float* __restrict__ bh,
    const float* __restrict__ c0, float* __restrict__ out,
    float* __restrict__ hstate, int t0, int TC) {
  extern __shared__ char lds[];          // [0,131072): Wc frags; [131072,+16384): hb dbuf
  char* hbase = lds + 131072;
  int tid = threadIdx.x;
  int w = tid >> 6, l = tid & 63, lr = l & 15, lq = l >> 4;
  int bg = blockIdx.x, b0 = bg << 4;

  // stage Wc into LDS (frag-major already)
  #pragma unroll 4
  for (int it = 0; it < 16; ++it)
    *(uint4*)(lds + it * 8192 + tid * 16) =
        *(const uint4*)((const char*)wcf + it * 8192 + tid * 16);

  // Wh R,N fragments -> registers, resident across all timesteps (128 VGPR)
  const bf16* whbase = whf + lq * 128 + lr * 8;
  bf16x8 whR[2][8], whN[2][8];
  #pragma unroll
  for (int i = 0; i < 2; ++i)
    #pragma unroll
    for (int k = 0; k < 8; ++k) {
      whR[i][k] = *(const bf16x8*)(whbase + ((w * 2 + i) * 8 + k) * 512);
      whN[i][k] = *(const bf16x8*)(whbase + ((16 + w * 2 + i) * 8 + k) * 512);
    }
  float bN[2], cA[2];
  #pragma unroll
  for (int i = 0; i < 2; ++i) {
    bN[i] = bh[512 + w * 32 + i * 16 + lr];
    cA[i] = c0[w * 32 + i * 16 + lr];
  }

  float h[2][4];
  if (t0 == 0) {
    #pragma unroll
    for (int i = 0; i < 2; ++i)
      #pragma unroll
      for (int j = 0; j < 4; ++j) h[i][j] = 0.f;
  } else {
    #pragma unroll
    for (int i = 0; i < 2; ++i)
      #pragma unroll
      for (int j = 0; j < 4; ++j)
        h[i][j] = hstate[(size_t)(b0 + lq * 4 + j) * Hsz + w * 32 + i * 16 + lr];
  }
  #pragma unroll
  for (int i = 0; i < 2; ++i) {
    int colb = (2 * i + (lr >> 3)) & 3;
    char* hw = hbase + w * 1024 + colb * 256 + (lr & 7) * 2 + lq * 64;
    #pragma unroll
    for (int j = 0; j < 4; ++j) *(bf16*)(hw + j * 16) = (bf16)h[i][j];
  }
  __syncthreads();

  const char* gxb = (const char*)gx + (size_t)bg * SLAB;
  // prefetched gx operands for current step
  uint2 irv[2], inv[2], aiv[2];
  #pragma unroll
  for (int i = 0; i < 2; ++i) {
    int off = (w * 2 + i) * 512 + lq * 128 + lr * 8;
    irv[i] = *(const uint2*)(gxb + off);
    inv[i] = *(const uint2*)(gxb + 8192 + off);
    aiv[i] = *(const uint2*)(gxb + 16384 + off);
  }

  for (int t = 0; t < TC; ++t) {
    int cur = t & 1, nxt = cur ^ 1;
    // ---- LDS reads of h (A-frags) ----
    const char* hr = hbase + cur * 8192 + lq * 256 + lr * 16;
    bf16x8 Ah[8];
    #pragma unroll
    for (int kk = 0; kk < 8; ++kk) Ah[kk] = *(const bf16x8*)(hr + kk * 1024);
    // ---- prefetch next step's gx operands (a full step of latency to hide) ----
    uint2 irn[2], inn[2], ain[2];
    bool pf = (t + 1 < TC);
    if (pf) {
      const char* slab = gxb + (size_t)(t + 1) * (64 * SLAB);
      #pragma unroll
      for (int i = 0; i < 2; ++i) {
        int off = (w * 2 + i) * 512 + lq * 128 + lr * 8;
        irn[i] = *(const uint2*)(slab + off);
        inn[i] = *(const uint2*)(slab + 8192 + off);
        ain[i] = *(const uint2*)(slab + 16384 + off);
      }
    }
    // ---- 48 MFMA: gh_R, gh_N (reg weights) + att_h (Wc from LDS) ----
    f32x4 accR[2], accN[2], accA[2];
    #pragma unroll
    for (int i = 0; i < 2; ++i)
      #pragma unroll
      for (int e = 0; e < 4; ++e) {
        accR[i][e] = 0.f; accN[i][e] = bN[i]; accA[i][e] = cA[i];
      }
    #pragma unroll
    for (int kk = 0; kk < 8; ++kk) {
      bf16x8 Ahk = Ah[kk];
      accR[0] = __builtin_amdgcn_mfma_f32_16x16x32_bf16(Ahk, whR[0][kk], accR[0], 0, 0, 0);
      accR[1] = __builtin_amdgcn_mfma_f32_16x16x32_bf16(Ahk, whR[1][kk], accR[1], 0, 0, 0);
      accN[0] = __builtin_amdgcn_mfma_f32_16x16x32_bf16(Ahk, whN[0][kk], accN[0], 0, 0, 0);
      accN[1] = __builtin_amdgcn_mfma_f32_16x16x32_bf16(Ahk, whN[1][kk], accN[1], 0, 0, 0);
      bf16x8 wc0 = *(const bf16x8*)(lds + ((w * 2 + 0) * 8 + kk) * 1024 + lq * 256 + lr * 16);
      accA[0] = __builtin_amdgcn_mfma_f32_16x16x32_bf16(Ahk, wc0, accA[0], 0, 0, 0);
      bf16x8 wc1 = *(const bf16x8*)(lds + ((w * 2 + 1) * 8 + kk) * 1024 + lq * 256 + lr * 16);
      accA[1] = __builtin_amdgcn_mfma_f32_16x16x32_bf16(Ahk, wc1, accA[1], 0, 0, 0);
    }
    // ---- gates in registers ----
    #pragma unroll
    for (int i = 0; i < 2; ++i) {
      union { uint2 u; bf16 v[4]; } ir, in_, ai;
      ir.u = irv[i]; in_.u = inv[i]; ai.u = aiv[i];
      #pragma unroll
      for (int j = 0; j < 4; ++j) {
        float rg = sigm(bf2f(ir.v[j]) + accR[i][j]);
        float xx = bf2f(in_.v[j]) + rg * accN[i][j];
        xx = fminf(fmaxf(xx, -15.f), 15.f);
        float e2 = exp2f(-2.885390081777927f * xx);
        float ng = (1.f - e2) * __builtin_amdgcn_rcpf(1.f + e2);
        float ig = sigm(bf2f(ai.v[j]) + accA[i][j]);
        float hy = ng + ig * (h[i][j] - ng);
        h[i][j] = hy;
        out[((size_t)(b0 + lq * 4 + j) * Tsz + (t0 + t)) * Hsz + (w * 32 + i * 16 + lr)] = hy;
      }
      int colb = (2 * i + (lr >> 3)) & 3;
      char* hw = hbase + nxt * 8192 + w * 1024 + colb * 256 + (lr & 7) * 2 + lq * 64;
      #pragma unroll
      for (int j = 0; j < 4; ++j) *(bf16*)(hw + j * 16) = (bf16)h[i][j];
    }
    if (pf) {
      #pragma unroll
      for (int i = 0; i < 2; ++i) { irv[i] = irn[i]; inv[i] = inn[i]; aiv[i] = ain[i]; }
    }
    __syncthreads();
  }
  // persist h for next chunk launch
  #pragma unroll
  for (int i = 0; i < 2; ++i)
    #pragma unroll
    for (int j = 0; j < 4; ++j)
      hstate[(size_t)(b0 + lq * 4 + j) * Hsz + w * 32 + i * 16 + lr] = h[i][j];
}

extern "C" void kernel_launch(void* const* d_in, const int* in_sizes, int n_in,
                              void* d_out, int out_size, void* d_ws, size_t ws_size,
                              hipStream_t stream) {
  (void)in_sizes; (void)n_in; (void)out_size;
  const float* x  = (const float*)d_in[0];
  const float* Wx = (const float*)d_in[1];
  const float* bx = (const float*)d_in[2];
  const float* Wh = (const float*)d_in[3];
  const float* bh = (const float*)d_in[4];
  const float* Wa = (const float*)d_in[5];
  const float* ba = (const float*)d_in[6];
  float* out = (float*)d_out;
  char* ws = (char*)d_ws;

  bf16* wxf = (bf16*)ws;                        // 48 tiles * 8KB = 393216 B (R,N,Wp)
  bf16* whf = (bf16*)(ws + 393216);             // 262144 B (R + N)
  bf16* wcf = (bf16*)(ws + 655360);             // 131072 B
  float* c0 = (float*)(ws + 786432);            // 1024 B
  float* hstate = (float*)(ws + 1048576);       // 1 MB
  bf16* gxbuf = (bf16*)(ws + 2097152);

  size_t avail = (ws_size > 2097152) ? ws_size - 2097152 : 0;
  size_t per_t = (size_t)64 * SLAB;             // 1.5 MB per timestep
  long tcl = (long)(avail / per_t);
  int TC = (tcl > Tsz) ? Tsz : (int)tcl;
  TC &= ~63;
  if (TC < 64) TC = 64;

  (void)hipFuncSetAttribute((const void*)k_phase2,
                            hipFuncAttributeMaxDynamicSharedMemorySize, 147456);

  k_repack<<<dim3(128), dim3(256), 0, stream>>>(Wx, Wh, wxf, whf);
  k_wc<<<dim3(256), dim3(256), 0, stream>>>(Wa, Wh, Wx, bh, bx, ba, wcf, wxf, c0);
  for (int t0 = 0; t0 < Tsz; t0 += TC) {
    int tc = Tsz - t0; if (tc > TC) tc = TC;
    k_phase1<<<dim3(64, tc / 16), dim3(256), 0, stream>>>(x, wxf, bx, bh, gxbuf, t0);
    k_phase2<<<dim3(64), dim3(512), 147456, stream>>>(gxbuf, whf, wcf, bh, c0, out, hstate, t0, tc);
  }
}